// Round 3
// baseline (152.919 us; speedup 1.0000x reference)
//
#include <hip/hip_runtime.h>
#include <hip/hip_bf16.h>
#include <stdint.h>

// Shapes (fixed): S=4, B=2, F=64, P=16, T=32, H=64, W=64, HID=32
#define THW   131072   // 32*64*64
#define NS    4
#define NB    2
#define NF    64
#define NP    16
#define HID   32
#define BN_EPS 1e-5f

typedef short  bf16x8  __attribute__((ext_vector_type(8)));   // 8 bf16 in 4 VGPRs
typedef float  f32x16  __attribute__((ext_vector_type(16)));

union FragU { uint32_t u[4]; bf16x8 v; uint4 q; };

__device__ __forceinline__ uint32_t pk2(float a, float b) {
    // single v_cvt_pk_bf16_f32 (RNE), a = low half
    __hip_bfloat162 h = __float22bfloat162_rn(make_float2(a, b));
    uint32_t r;
    __builtin_memcpy(&r, &h, sizeof(r));   // __hip_bfloat162 not trivially copyable -> memcpy
    return r;
}

// One wave = 32 pixels. lane&31 = pixel column; lane>>5 = K-half (MFMA frag k = 8*hi + j).
__global__ __launch_bounds__(256, 4) void gssm_kernel(
    const float* __restrict__ feats, const float* __restrict__ ps,
    const float* __restrict__ w1,    const float* __restrict__ gamma,
    const float* __restrict__ beta,  const float* __restrict__ mean,
    const float* __restrict__ var,   const float* __restrict__ w2,
    float* __restrict__ out)
{
    // w1 staged as packed bf16 pairs: [o][k*8 + hi*4 + r], row stride 44 dwords
    // (16B-aligned per-lane uint4 reads; 12*ln mod 32 start-bank spread)
    __shared__ __align__(16) uint32_t w1lds[32 * 44];
    __shared__ float4 tbl[HID];   // {scale, shift, w2, pad}

    const int tid = threadIdx.x;
    for (int t = tid; t < 1280; t += 256) {          // 2560 floats = 1280 pairs
        float2 v = ((const float2*)w1)[t];
        int o = t / 40, cp = t - o * 40;             // 40 pairs per row
        int k = cp >> 3, rem = cp & 7;               // rem = hi*4 + r
        w1lds[o * 44 + k * 8 + rem] = pk2(v.x, v.y);
    }
    if (tid < HID) {
        float sc = gamma[tid] * rsqrtf(var[tid] + BN_EPS);
        float sh = beta[tid] - mean[tid] * sc;
        tbl[tid] = make_float4(sc, sh, w2[tid], 0.f);
    }
    __syncthreads();

    const int lane = tid & 63;
    const int wv   = tid >> 6;
    const int hi   = lane >> 5;
    const int ln   = lane & 31;

    const int tile = blockIdx.x * 4 + wv;      // 8192 tiles of 32 pixels
    const int pix0 = tile * 32;
    const int b    = pix0 >> 17;               // THW = 2^17
    const int thw  = (pix0 & (THW - 1)) + ln;

    const uint32_t abase = (uint32_t)(ln * 44 + hi * 4);   // dword index into w1lds

    // ---- packed p-fragment (persists, 4 regs)
    FragU bp;
    {
        const float* pb = ps + ((long)(b * NP + hi * 8)) * THW + thw;
        float pv[8];
        #pragma unroll
        for (int r = 0; r < 8; ++r) pv[r] = pb[(long)r * THW];
        #pragma unroll
        for (int r = 0; r < 4; ++r) bp.u[r] = pk2(pv[2 * r], pv[2 * r + 1]);
    }

    float num[32];
    #pragma unroll
    for (int i = 0; i < 32; ++i) num[i] = 0.f;
    float mrun = -1e30f, den = 0.f;
    float lg[4];

    #pragma unroll
    for (int s = 0; s < NS; ++s) {
        const float* fb = feats + ((long)((s * NB + b) * NF + hi * 8)) * THW + thw;

        // load 32 feats values, pack to 4 bf16x8 fragments (16 regs, kept for num)
        FragU pkk[4];
        #pragma unroll
        for (int k = 0; k < 4; ++k) {
            float fv[8];
            #pragma unroll
            for (int j = 0; j < 8; ++j)
                fv[j] = fb[(long)(k * 16 + j) * THW];
            #pragma unroll
            for (int r = 0; r < 4; ++r)
                pkk[k].u[r] = pk2(fv[2 * r], fv[2 * r + 1]);
        }

        f32x16 acc;
        #pragma unroll
        for (int r = 0; r < 16; ++r) acc[r] = 0.f;

        {   // p-term: A fragment k=4 from LDS
            FragU af; af.q = *((const uint4*)&w1lds[abase + 4 * 8]);
            acc = __builtin_amdgcn_mfma_f32_32x32x16_bf16(af.v, bp.v, acc, 0, 0, 0);
        }
        #pragma unroll
        for (int k = 0; k < 4; ++k) {
            FragU af; af.q = *((const uint4*)&w1lds[abase + k * 8]);
            acc = __builtin_amdgcn_mfma_f32_32x32x16_bf16(af.v, pkk[k].v, acc, 0, 0, 0);
        }

        // logit = sum_o relu(h*scale+shift)*w2 ; C/D row = (r&3)+8*(r>>2)+4*hi
        float part = 0.f;
        #pragma unroll
        for (int r = 0; r < 16; ++r) {
            const int row = (r & 3) + 8 * (r >> 2) + 4 * hi;
            float4 t = tbl[row];
            float h = fmaxf(fmaf(acc[r], t.x, t.y), 0.f);
            part = fmaf(h, t.z, part);
        }
        const float logit = part + __shfl_xor(part, 32);
        lg[s] = logit;

        // online softmax accumulate (b2 shift-invariant: skipped)
        const float mn  = fmaxf(mrun, logit);
        const float rsc = __expf(mrun - mn);
        const float e   = __expf(logit - mn);
        den = den * rsc + e;
        #pragma unroll
        for (int k = 0; k < 4; ++k)
            #pragma unroll
            for (int r = 0; r < 4; ++r) {
                const float flo = __builtin_bit_cast(float, pkk[k].u[r] << 16);
                const float fhi = __builtin_bit_cast(float, pkk[k].u[r] & 0xFFFF0000u);
                num[k * 8 + 2 * r]     = fmaf(num[k * 8 + 2 * r],     rsc, e * flo);
                num[k * 8 + 2 * r + 1] = fmaf(num[k * 8 + 2 * r + 1], rsc, e * fhi);
            }
        mrun = mn;
    }

    const float inv = 1.f / den;

    // ---- out[b][f][thw], f = k*16 + hi*8 + j
    float* ob = out + ((long)(b * NF + hi * 8)) * THW + thw;
    #pragma unroll
    for (int k = 0; k < 4; ++k)
        #pragma unroll
        for (int j = 0; j < 8; ++j)
            ob[(long)(k * 16 + j) * THW] = num[k * 8 + j] * inv;

    // ---- alpha[b][s][thw] at offset B*F*THW; hi=0 -> s=0,1 ; hi=1 -> s=2,3
    const float la = hi ? lg[2] : lg[0];
    const float lb = hi ? lg[3] : lg[1];
    float* ab = out + (long)NB * NF * THW + ((long)(b * NS + hi * 2)) * THW + thw;
    ab[0]   = __expf(la - mrun) * inv;
    ab[THW] = __expf(lb - mrun) * inv;
}

extern "C" void kernel_launch(void* const* d_in, const int* in_sizes, int n_in,
                              void* d_out, int out_size, void* d_ws, size_t ws_size,
                              hipStream_t stream) {
    const float* feats = (const float*)d_in[0];
    const float* ps    = (const float*)d_in[1];
    const float* w1    = (const float*)d_in[2];
    const float* gamma = (const float*)d_in[3];
    const float* beta  = (const float*)d_in[4];
    const float* mean  = (const float*)d_in[5];
    const float* var   = (const float*)d_in[6];
    const float* w2    = (const float*)d_in[7];
    float* out = (float*)d_out;

    dim3 grid(2048), block(256);   // 8192 waves = 8192 tiles of 32 pixels
    hipLaunchKernelGGL(gssm_kernel, grid, block, 0, stream,
                       feats, ps, w1, gamma, beta, mean, var, w2, out);
}

// Round 4
// 140.506 us; speedup vs baseline: 1.0883x; 1.0883x over previous
//
#include <hip/hip_runtime.h>
#include <hip/hip_bf16.h>
#include <stdint.h>

// Shapes (fixed): S=4, B=2, F=64, P=16, T=32, H=64, W=64, HID=32
#define THW   131072   // 32*64*64
#define NS    4
#define NB    2
#define NF    64
#define NP    16
#define HID   32
#define BN_EPS 1e-5f

typedef short  bf16x8  __attribute__((ext_vector_type(8)));   // 8 bf16 in 4 VGPRs
typedef float  f32x16  __attribute__((ext_vector_type(16)));

union FragU { uint32_t u[4]; bf16x8 v; uint4 q; };

__device__ __forceinline__ uint32_t pk2(float a, float b) {
    // single v_cvt_pk_bf16_f32 (RNE), a = low half
    __hip_bfloat162 h = __float22bfloat162_rn(make_float2(a, b));
    uint32_t r;
    __builtin_memcpy(&r, &h, sizeof(r));
    return r;
}

// One wave = 32 pixels. lane&31 = pixel column; lane>>5 = K-half (MFMA frag k = 8*hi + j).
// launch_bounds(256,3): VGPR cap ~170 — fits live set (~115) + one s-iteration of
// load pipelining without scratch spill (cap 128 spilled: R3 showed +160MB WRITE).
__global__ __launch_bounds__(256, 3) void gssm_kernel(
    const float* __restrict__ feats, const float* __restrict__ ps,
    const float* __restrict__ w1,    const float* __restrict__ gamma,
    const float* __restrict__ beta,  const float* __restrict__ mean,
    const float* __restrict__ var,   const float* __restrict__ w2,
    float* __restrict__ out)
{
    // w1 staged as packed bf16 pairs: [o][k*8 + hi*4 + r], row stride 44 dwords
    __shared__ __align__(16) uint32_t w1lds[32 * 44];
    __shared__ float4 tbl[HID];   // {scale, shift, w2, pad}

    const int tid = threadIdx.x;
    for (int t = tid; t < 1280; t += 256) {          // 2560 floats = 1280 pairs
        float2 v = ((const float2*)w1)[t];
        int o = t / 40, cp = t - o * 40;             // 40 pairs per row
        int k = cp >> 3, rem = cp & 7;               // rem = hi*4 + r
        w1lds[o * 44 + k * 8 + rem] = pk2(v.x, v.y);
    }
    if (tid < HID) {
        float sc = gamma[tid] * rsqrtf(var[tid] + BN_EPS);
        float sh = beta[tid] - mean[tid] * sc;
        tbl[tid] = make_float4(sc, sh, w2[tid], 0.f);
    }
    __syncthreads();

    const int lane = tid & 63;
    const int wv   = tid >> 6;
    const int hi   = lane >> 5;
    const int ln   = lane & 31;

    const int tile = blockIdx.x * 4 + wv;      // 8192 tiles of 32 pixels
    const int pix0 = tile * 32;
    const int b    = pix0 >> 17;               // THW = 2^17
    const int thw  = (pix0 & (THW - 1)) + ln;

    const uint32_t abase = (uint32_t)(ln * 44 + hi * 4);   // dword index into w1lds

    // ---- packed p-fragment (persists, 4 regs)
    FragU bp;
    {
        const float* pb = ps + ((long)(b * NP + hi * 8)) * THW + thw;
        float pv[8];
        #pragma unroll
        for (int r = 0; r < 8; ++r) pv[r] = pb[(long)r * THW];
        #pragma unroll
        for (int r = 0; r < 4; ++r) bp.u[r] = pk2(pv[2 * r], pv[2 * r + 1]);
    }

    float num[32];
    #pragma unroll
    for (int i = 0; i < 32; ++i) num[i] = 0.f;
    float mrun = -1e30f, den = 0.f;
    float lg[4];

    #pragma unroll
    for (int s = 0; s < NS; ++s) {
        const float* fb = feats + ((long)((s * NB + b) * NF + hi * 8)) * THW + thw;

        // load 32 feats values, pack to 4 bf16x8 fragments (16 regs, kept for num)
        FragU pkk[4];
        #pragma unroll
        for (int k = 0; k < 4; ++k) {
            float fv[8];
            #pragma unroll
            for (int j = 0; j < 8; ++j)
                fv[j] = fb[(long)(k * 16 + j) * THW];
            #pragma unroll
            for (int r = 0; r < 4; ++r)
                pkk[k].u[r] = pk2(fv[2 * r], fv[2 * r + 1]);
        }

        f32x16 acc;
        #pragma unroll
        for (int r = 0; r < 16; ++r) acc[r] = 0.f;

        {   // p-term: A fragment k=4 from LDS
            FragU af; af.q = *((const uint4*)&w1lds[abase + 4 * 8]);
            acc = __builtin_amdgcn_mfma_f32_32x32x16_bf16(af.v, bp.v, acc, 0, 0, 0);
        }
        #pragma unroll
        for (int k = 0; k < 4; ++k) {
            FragU af; af.q = *((const uint4*)&w1lds[abase + k * 8]);
            acc = __builtin_amdgcn_mfma_f32_32x32x16_bf16(af.v, pkk[k].v, acc, 0, 0, 0);
        }

        // logit = sum_o relu(h*scale+shift)*w2 ; C/D row = (r&3)+8*(r>>2)+4*hi
        float part = 0.f;
        #pragma unroll
        for (int r = 0; r < 16; ++r) {
            const int row = (r & 3) + 8 * (r >> 2) + 4 * hi;
            float4 t = tbl[row];
            float h = fmaxf(fmaf(acc[r], t.x, t.y), 0.f);
            part = fmaf(h, t.z, part);
        }
        const float logit = part + __shfl_xor(part, 32);
        lg[s] = logit;

        // online softmax accumulate (b2 shift-invariant: skipped)
        const float mn  = fmaxf(mrun, logit);
        const float rsc = __expf(mrun - mn);
        const float e   = __expf(logit - mn);
        den = den * rsc + e;
        #pragma unroll
        for (int k = 0; k < 4; ++k)
            #pragma unroll
            for (int r = 0; r < 4; ++r) {
                const float flo = __builtin_bit_cast(float, pkk[k].u[r] << 16);
                const float fhi = __builtin_bit_cast(float, pkk[k].u[r] & 0xFFFF0000u);
                num[k * 8 + 2 * r]     = fmaf(num[k * 8 + 2 * r],     rsc, e * flo);
                num[k * 8 + 2 * r + 1] = fmaf(num[k * 8 + 2 * r + 1], rsc, e * fhi);
            }
        mrun = mn;
    }

    const float inv = 1.f / den;

    // ---- out[b][f][thw], f = k*16 + hi*8 + j
    float* ob = out + ((long)(b * NF + hi * 8)) * THW + thw;
    #pragma unroll
    for (int k = 0; k < 4; ++k)
        #pragma unroll
        for (int j = 0; j < 8; ++j)
            ob[(long)(k * 16 + j) * THW] = num[k * 8 + j] * inv;

    // ---- alpha[b][s][thw] at offset B*F*THW; hi=0 -> s=0,1 ; hi=1 -> s=2,3
    const float la = hi ? lg[2] : lg[0];
    const float lb = hi ? lg[3] : lg[1];
    float* ab = out + (long)NB * NF * THW + ((long)(b * NS + hi * 2)) * THW + thw;
    ab[0]   = __expf(la - mrun) * inv;
    ab[THW] = __expf(lb - mrun) * inv;
}

extern "C" void kernel_launch(void* const* d_in, const int* in_sizes, int n_in,
                              void* d_out, int out_size, void* d_ws, size_t ws_size,
                              hipStream_t stream) {
    const float* feats = (const float*)d_in[0];
    const float* ps    = (const float*)d_in[1];
    const float* w1    = (const float*)d_in[2];
    const float* gamma = (const float*)d_in[3];
    const float* beta  = (const float*)d_in[4];
    const float* mean  = (const float*)d_in[5];
    const float* var   = (const float*)d_in[6];
    const float* w2    = (const float*)d_in[7];
    float* out = (float*)d_out;

    dim3 grid(2048), block(256);   // 8192 waves = 8192 tiles of 32 pixels
    hipLaunchKernelGGL(gssm_kernel, grid, block, 0, stream,
                       feats, ps, w1, gamma, beta, mean, var, w2, out);
}

// Round 6
// 94.389 us; speedup vs baseline: 1.6201x; 1.4886x over previous
//
#include <hip/hip_runtime.h>
#include <hip/hip_bf16.h>
#include <stdint.h>

// Shapes (fixed): S=4, B=2, F=64, P=16, T=32, H=64, W=64, HID=32
#define THW   131072   // 32*64*64
#define NS    4
#define NB    2
#define NF    64
#define NP    16
#define HID   32
#define BN_EPS 1e-5f

typedef short  bf16x8  __attribute__((ext_vector_type(8)));   // 8 bf16 in 4 VGPRs
typedef float  f32x16  __attribute__((ext_vector_type(16)));

union FragU { uint32_t u[4]; bf16x8 v; uint4 q; };

__device__ __forceinline__ uint32_t pk2(float a, float b) {
    // single v_cvt_pk_bf16_f32 (RNE), a = low half
    __hip_bfloat162 h = __float22bfloat162_rn(make_float2(a, b));
    uint32_t r;
    __builtin_memcpy(&r, &h, sizeof(r));
    return r;
}
__device__ __forceinline__ float lo16(uint32_t u) { return __builtin_bit_cast(float, u << 16); }
__device__ __forceinline__ float hi16(uint32_t u) { return __builtin_bit_cast(float, u & 0xFFFF0000u); }

// One wave = 32 pixels. lane&31 = pixel; lane>>5 = K-half (MFMA frag k = 8*hi + j).
// (256,2): the ONLY spill-free bound — (256,3)/(256,4) trigger an 84/84 or 64/64
// VGPR/AGPR split and scratch-spill (R3: +160MB, R4: +86MB WRITE_SIZE).
// NOTE: tbl values are NOT wave-uniform (row depends on hi = lane>>5) — per-lane
// loads only, no readfirstlane (R5 failed exactly on that).
__global__ __launch_bounds__(256, 2) void gssm_kernel(
    const float* __restrict__ feats, const float* __restrict__ ps,
    const float* __restrict__ w1,    const float* __restrict__ gamma,
    const float* __restrict__ beta,  const float* __restrict__ mean,
    const float* __restrict__ var,   const float* __restrict__ w2,
    float* __restrict__ out)
{
    // w1*scale staged as packed bf16 pairs: [o][kblk*8 + hi*4 + r], row stride 44
    __shared__ __align__(16) uint32_t w1lds[32 * 44];
    __shared__ float2 tbl[HID];   // {shift, w2}

    const int tid = threadIdx.x;
    for (int t = tid; t < 1280; t += 256) {          // 2560 floats = 1280 pairs
        float2 v = ((const float2*)w1)[t];
        int o = t / 40, cp = t - o * 40;             // 40 pairs per w1 row
        float sc = gamma[o] * rsqrtf(var[o] + BN_EPS);   // fold BN scale into A
        w1lds[o * 44 + (cp >> 3) * 8 + (cp & 7)] = pk2(v.x * sc, v.y * sc);
    }
    if (tid < HID) {
        float sc = gamma[tid] * rsqrtf(var[tid] + BN_EPS);
        tbl[tid] = make_float2(beta[tid] - mean[tid] * sc, w2[tid]);
    }
    __syncthreads();

    const int lane = tid & 63;
    const int wv   = tid >> 6;
    const int hi   = lane >> 5;
    const int ln   = lane & 31;

    const int tile = blockIdx.x * 4 + wv;      // 8192 tiles of 32 pixels
    const int pix0 = tile * 32;
    const int b    = pix0 >> 17;               // THW = 2^17
    const int thw  = (pix0 & (THW - 1)) + ln;

    // ---- hoist A fragments (w1*scale, bf16) : 5 frags x 4 regs = 20 VGPR
    FragU afr[5];
    {
        const uint32_t abase = (uint32_t)(ln * 44 + hi * 4);
        #pragma unroll
        for (int k = 0; k < 5; ++k)
            afr[k].q = *((const uint4*)&w1lds[abase + k * 8]);
    }
    // ---- hoist {shift, w2} for this thread's 16 C/D rows (PER-LANE: row depends on hi)
    float sh[16], wo[16];
    #pragma unroll
    for (int r = 0; r < 16; ++r) {
        float2 t = tbl[(r & 3) + 8 * (r >> 2) + 4 * hi];
        sh[r] = t.x;
        wo[r] = t.y;
    }

    // ---- p-term accumulator (shared by all s): 1 MFMA, kept in 16 regs
    f32x16 accp;
    #pragma unroll
    for (int r = 0; r < 16; ++r) accp[r] = 0.f;
    {
        FragU bp;
        const float* pb = ps + ((long)(b * NP + hi * 8)) * THW + thw;
        float pv[8];
        #pragma unroll
        for (int r = 0; r < 8; ++r) pv[r] = pb[(long)r * THW];
        #pragma unroll
        for (int r = 0; r < 4; ++r) bp.u[r] = pk2(pv[2 * r], pv[2 * r + 1]);
        accp = __builtin_amdgcn_mfma_f32_32x32x16_bf16(afr[4].v, bp.v, accp, 0, 0, 0);
    }

    // ---- 4 logits, keeping packed feats fragments (4 x 16 regs)
    FragU pkkS[NS][4];
    float lg[NS];

    #pragma unroll
    for (int s = 0; s < NS; ++s) {
        const float* fb = feats + ((long)((s * NB + b) * NF + hi * 8)) * THW + thw;

        float fv[32];
        #pragma unroll
        for (int k = 0; k < 4; ++k)
            #pragma unroll
            for (int j = 0; j < 8; ++j)
                fv[k * 8 + j] = fb[(long)(k * 16 + j) * THW];
        #pragma unroll
        for (int k = 0; k < 4; ++k)
            #pragma unroll
            for (int r = 0; r < 4; ++r)
                pkkS[s][k].u[r] = pk2(fv[k * 8 + 2 * r], fv[k * 8 + 2 * r + 1]);

        f32x16 acc = accp;
        #pragma unroll
        for (int k = 0; k < 4; ++k)
            acc = __builtin_amdgcn_mfma_f32_32x32x16_bf16(afr[k].v, pkkS[s][k].v, acc, 0, 0, 0);

        float part = 0.f;
        #pragma unroll
        for (int r = 0; r < 16; ++r)
            part = fmaf(fmaxf(acc[r] + sh[r], 0.f), wo[r], part);
        lg[s] = part + __shfl_xor(part, 32);
    }

    // ---- softmax over 4 logits (b2 shift-invariant: skipped)
    const float m   = fmaxf(fmaxf(lg[0], lg[1]), fmaxf(lg[2], lg[3]));
    const float e0  = __expf(lg[0] - m), e1 = __expf(lg[1] - m);
    const float e2  = __expf(lg[2] - m), e3 = __expf(lg[3] - m);
    const float inv = 1.f / (e0 + e1 + e2 + e3);
    const float a0 = e0 * inv, a1 = e1 * inv, a2 = e2 * inv, a3 = e3 * inv;

    // ---- out[b][f][thw] = sum_s alpha_s * feats_s (from bf16 frags), f = k*16+hi*8+j
    float* ob = out + ((long)(b * NF + hi * 8)) * THW + thw;
    #pragma unroll
    for (int k = 0; k < 4; ++k)
        #pragma unroll
        for (int r = 0; r < 4; ++r) {
            float vlo = a0 * lo16(pkkS[0][k].u[r]);
            float vhi = a0 * hi16(pkkS[0][k].u[r]);
            vlo = fmaf(a1, lo16(pkkS[1][k].u[r]), vlo);
            vhi = fmaf(a1, hi16(pkkS[1][k].u[r]), vhi);
            vlo = fmaf(a2, lo16(pkkS[2][k].u[r]), vlo);
            vhi = fmaf(a2, hi16(pkkS[2][k].u[r]), vhi);
            vlo = fmaf(a3, lo16(pkkS[3][k].u[r]), vlo);
            vhi = fmaf(a3, hi16(pkkS[3][k].u[r]), vhi);
            ob[(long)(k * 16 + 2 * r)     * THW] = vlo;
            ob[(long)(k * 16 + 2 * r + 1) * THW] = vhi;
        }

    // ---- alpha[b][s][thw] at offset B*F*THW; hi=0 -> s=0,1 ; hi=1 -> s=2,3
    float* ab = out + (long)NB * NF * THW + ((long)(b * NS + hi * 2)) * THW + thw;
    ab[0]   = hi ? a2 : a0;
    ab[THW] = hi ? a3 : a1;
}

extern "C" void kernel_launch(void* const* d_in, const int* in_sizes, int n_in,
                              void* d_out, int out_size, void* d_ws, size_t ws_size,
                              hipStream_t stream) {
    const float* feats = (const float*)d_in[0];
    const float* ps    = (const float*)d_in[1];
    const float* w1    = (const float*)d_in[2];
    const float* gamma = (const float*)d_in[3];
    const float* beta  = (const float*)d_in[4];
    const float* mean  = (const float*)d_in[5];
    const float* var   = (const float*)d_in[6];
    const float* w2    = (const float*)d_in[7];
    float* out = (float*)d_out;

    dim3 grid(2048), block(256);   // 8192 waves = 8192 tiles of 32 pixels
    hipLaunchKernelGGL(gssm_kernel, grid, block, 0, stream,
                       feats, ps, w1, gamma, beta, mean, var, w2, out);
}

// Round 7
// 93.994 us; speedup vs baseline: 1.6269x; 1.0042x over previous
//
#include <hip/hip_runtime.h>
#include <hip/hip_bf16.h>
#include <stdint.h>

// Shapes (fixed): S=4, B=2, F=64, P=16, T=32, H=64, W=64, HID=32
#define THW   131072   // 32*64*64
#define NS    4
#define NB    2
#define NF    64
#define NP    16
#define HID   32
#define BN_EPS 1e-5f

typedef short  bf16x8  __attribute__((ext_vector_type(8)));   // 8 bf16 in 4 VGPRs
typedef float  f32x16  __attribute__((ext_vector_type(16)));

union FragU { uint32_t u[4]; bf16x8 v; uint4 q; };

__device__ __forceinline__ uint32_t pk2(float a, float b) {
    __hip_bfloat162 h = __float22bfloat162_rn(make_float2(a, b));
    uint32_t r;
    __builtin_memcpy(&r, &h, sizeof(r));
    return r;
}
__device__ __forceinline__ float lo16(uint32_t u) { return __builtin_bit_cast(float, u << 16); }
__device__ __forceinline__ float hi16(uint32_t u) { return __builtin_bit_cast(float, u & 0xFFFF0000u); }

// One wave = 32 pixels. lane&31 = pixel; lane>>5 = K-half (MFMA frag k = 8*hi + j).
// (256,2): the ONLY spill-free bound — (256,3)/(256,4) trigger VGPR/AGPR-split
// scratch spill (R3: +160MB, R4: +86MB WRITE_SIZE).
// R7: explicit s-pipeline — issue s+1's 32 feats loads BEFORE s's MFMA/logit so
// loads stay in flight through compute (R6 showed ~60% load duty cycle = 3.7 TB/s).
// Freed regs for the prefetch buffer: tbl read per-use from LDS, p-term MFMA
// recomputed per s (no accp).
__global__ __launch_bounds__(256, 2) void gssm_kernel(
    const float* __restrict__ feats, const float* __restrict__ ps,
    const float* __restrict__ w1,    const float* __restrict__ gamma,
    const float* __restrict__ beta,  const float* __restrict__ mean,
    const float* __restrict__ var,   const float* __restrict__ w2,
    float* __restrict__ out)
{
    // w1*scale staged as packed bf16 pairs: [o][kblk*8 + hi*4 + r], row stride 44
    __shared__ __align__(16) uint32_t w1lds[32 * 44];
    __shared__ float2 tbl[HID];   // {shift, w2}

    const int tid = threadIdx.x;
    for (int t = tid; t < 1280; t += 256) {          // 2560 floats = 1280 pairs
        float2 v = ((const float2*)w1)[t];
        int o = t / 40, cp = t - o * 40;             // 40 pairs per w1 row
        float sc = gamma[o] * rsqrtf(var[o] + BN_EPS);   // fold BN scale into A
        w1lds[o * 44 + (cp >> 3) * 8 + (cp & 7)] = pk2(v.x * sc, v.y * sc);
    }
    if (tid < HID) {
        float sc = gamma[tid] * rsqrtf(var[tid] + BN_EPS);
        tbl[tid] = make_float2(beta[tid] - mean[tid] * sc, w2[tid]);
    }
    __syncthreads();

    const int lane = tid & 63;
    const int wv   = tid >> 6;
    const int hi   = lane >> 5;
    const int ln   = lane & 31;

    const int tile = blockIdx.x * 4 + wv;      // 8192 tiles of 32 pixels
    const int pix0 = tile * 32;
    const int b    = pix0 >> 17;               // THW = 2^17
    const int thw  = (pix0 & (THW - 1)) + ln;

    // ---- hoist A fragments (w1*scale, bf16): 5 x 4 regs
    FragU afr[5];
    {
        const uint32_t abase = (uint32_t)(ln * 44 + hi * 4);
        #pragma unroll
        for (int k = 0; k < 5; ++k)
            afr[k].q = *((const uint4*)&w1lds[abase + k * 8]);
    }

    // ---- packed p-fragment (4 regs, reused every s)
    FragU bp;
    {
        const float* pb = ps + ((long)(b * NP + hi * 8)) * THW + thw;
        float pv[8];
        #pragma unroll
        for (int r = 0; r < 8; ++r) pv[r] = pb[(long)r * THW];
        #pragma unroll
        for (int r = 0; r < 4; ++r) bp.u[r] = pk2(pv[2 * r], pv[2 * r + 1]);
    }

    const float* fbase = feats + ((long)(b * NF + hi * 8)) * THW + thw;
    const long   sstr  = (long)NB * NF * THW;

    auto issue = [&](int s, float* fv) {
        const float* fb = fbase + (long)s * sstr;
        #pragma unroll
        for (int k = 0; k < 4; ++k)
            #pragma unroll
            for (int j = 0; j < 8; ++j)
                fv[k * 8 + j] = fb[(long)(k * 16 + j) * THW];
    };
    auto pack = [&](FragU* pk, const float* fv) {
        #pragma unroll
        for (int k = 0; k < 4; ++k)
            #pragma unroll
            for (int r = 0; r < 4; ++r)
                pk[k].u[r] = pk2(fv[k * 8 + 2 * r], fv[k * 8 + 2 * r + 1]);
    };
    auto logit = [&](const FragU* pk) -> float {
        f32x16 acc;
        #pragma unroll
        for (int r = 0; r < 16; ++r) acc[r] = 0.f;
        acc = __builtin_amdgcn_mfma_f32_32x32x16_bf16(afr[4].v, bp.v,    acc, 0, 0, 0);
        acc = __builtin_amdgcn_mfma_f32_32x32x16_bf16(afr[0].v, pk[0].v, acc, 0, 0, 0);
        acc = __builtin_amdgcn_mfma_f32_32x32x16_bf16(afr[1].v, pk[1].v, acc, 0, 0, 0);
        acc = __builtin_amdgcn_mfma_f32_32x32x16_bf16(afr[2].v, pk[2].v, acc, 0, 0, 0);
        acc = __builtin_amdgcn_mfma_f32_32x32x16_bf16(afr[3].v, pk[3].v, acc, 0, 0, 0);
        float pp[4] = {0.f, 0.f, 0.f, 0.f};
        #pragma unroll
        for (int r = 0; r < 16; ++r) {
            float2 t = tbl[(r & 3) + 8 * (r >> 2) + 4 * hi];   // per-lane LDS read
            float h = fmaxf(acc[r] + t.x, 0.f);
            pp[r & 3] = fmaf(h, t.y, pp[r & 3]);               // const idx after unroll
        }
        float part = (pp[0] + pp[1]) + (pp[2] + pp[3]);
        return part + __shfl_xor(part, 32);
    };

    // ---- software-pipelined s loop: issue(s+1) before compute(s)
    float fvA[32], fvB[32];
    FragU pk0[4], pk1[4], pk2f[4], pk3[4];
    float lg0, lg1, lg2, lg3;

    issue(0, fvA);
    pack(pk0, fvA);
    issue(1, fvB);          // in flight during logit0
    lg0 = logit(pk0);
    pack(pk1, fvB);
    issue(2, fvA);          // in flight during logit1
    lg1 = logit(pk1);
    pack(pk2f, fvA);
    issue(3, fvB);          // in flight during logit2
    lg2 = logit(pk2f);
    pack(pk3, fvB);
    lg3 = logit(pk3);

    // ---- softmax over 4 logits (b2 shift-invariant: skipped)
    const float m   = fmaxf(fmaxf(lg0, lg1), fmaxf(lg2, lg3));
    const float e0  = __expf(lg0 - m), e1 = __expf(lg1 - m);
    const float e2  = __expf(lg2 - m), e3 = __expf(lg3 - m);
    const float inv = 1.f / (e0 + e1 + e2 + e3);
    const float a0 = e0 * inv, a1 = e1 * inv, a2 = e2 * inv, a3 = e3 * inv;

    // ---- out[b][f][thw] = sum_s alpha_s * feats_s (from bf16 frags), f = k*16+hi*8+j
    float* ob = out + ((long)(b * NF + hi * 8)) * THW + thw;
    #pragma unroll
    for (int k = 0; k < 4; ++k)
        #pragma unroll
        for (int r = 0; r < 4; ++r) {
            float vlo = a0 * lo16(pk0[k].u[r]);
            float vhi = a0 * hi16(pk0[k].u[r]);
            vlo = fmaf(a1, lo16(pk1[k].u[r]), vlo);
            vhi = fmaf(a1, hi16(pk1[k].u[r]), vhi);
            vlo = fmaf(a2, lo16(pk2f[k].u[r]), vlo);
            vhi = fmaf(a2, hi16(pk2f[k].u[r]), vhi);
            vlo = fmaf(a3, lo16(pk3[k].u[r]), vlo);
            vhi = fmaf(a3, hi16(pk3[k].u[r]), vhi);
            ob[(long)(k * 16 + 2 * r)     * THW] = vlo;
            ob[(long)(k * 16 + 2 * r + 1) * THW] = vhi;
        }

    // ---- alpha[b][s][thw] at offset B*F*THW; hi=0 -> s=0,1 ; hi=1 -> s=2,3
    float* ab = out + (long)NB * NF * THW + ((long)(b * NS + hi * 2)) * THW + thw;
    ab[0]   = hi ? a2 : a0;
    ab[THW] = hi ? a3 : a1;
}

extern "C" void kernel_launch(void* const* d_in, const int* in_sizes, int n_in,
                              void* d_out, int out_size, void* d_ws, size_t ws_size,
                              hipStream_t stream) {
    const float* feats = (const float*)d_in[0];
    const float* ps    = (const float*)d_in[1];
    const float* w1    = (const float*)d_in[2];
    const float* gamma = (const float*)d_in[3];
    const float* beta  = (const float*)d_in[4];
    const float* mean  = (const float*)d_in[5];
    const float* var   = (const float*)d_in[6];
    const float* w2    = (const float*)d_in[7];
    float* out = (float*)d_out;

    dim3 grid(2048), block(256);   // 8192 waves = 8192 tiles of 32 pixels
    hipLaunchKernelGGL(gssm_kernel, grid, block, 0, stream,
                       feats, ps, w1, gamma, beta, mean, var, w2, out);
}